// Round 6
// baseline (996.806 us; speedup 1.0000x reference)
//
#include <hip/hip_runtime.h>
#include <math.h>

// Problem constants
#define NN 20000
#define NE 320000
#define FD 128
#define RBFN 20
#define RC_ 5.0f
#define NITER 3
#define NMOL 64
#define F3 384
#define F2 256
#define PI_ 3.14159265358979323846f
#define KB 128
#define LPAD 8
#define SD_STRIDE 516   // u16 per sdrep edge row (129 ushort4) — de-alias banks

typedef __attribute__((ext_vector_type(8))) short  bf16x8;
typedef __attribute__((ext_vector_type(4))) float  floatx4;
typedef unsigned short u16;

__device__ __forceinline__ u16 f2b(float x) {
    union { float f; unsigned int u; } v; v.f = x;
    unsigned int u = v.u;
    return (u16)((u + 0x7fffu + ((u >> 16) & 1u)) >> 16);   // RNE
}
__device__ __forceinline__ float b2f(u16 x) {
    union { unsigned int u; float f; } v; v.u = ((unsigned int)x) << 16;
    return v.f;
}

// ---------------------------------------------------------------- weight cvt (once per launch)
__global__ __launch_bounds__(256) void cvt_w_kernel(
    const float* s0, int n0, const float* s1, int n1, const float* s2, int n2,
    const float* s3, int n3, const float* s4, int n4, const float* s5, int n5,
    const float* s6, int n6, u16* __restrict__ dst)
{
    int idx = blockIdx.x * 256 + threadIdx.x;
    if (idx < n0) { dst[idx] = f2b(s0[idx]); return; } idx -= n0; dst += n0;
    if (idx < n1) { dst[idx] = f2b(s1[idx]); return; } idx -= n1; dst += n1;
    if (idx < n2) { dst[idx] = f2b(s2[idx]); return; } idx -= n2; dst += n2;
    if (idx < n3) { dst[idx] = f2b(s3[idx]); return; } idx -= n3; dst += n3;
    if (idx < n4) { dst[idx] = f2b(s4[idx]); return; } idx -= n4; dst += n4;
    if (idx < n5) { dst[idx] = f2b(s5[idx]); return; } idx -= n5; dst += n5;
    if (idx < n6) { dst[idx] = f2b(s6[idx]); }
}

// ew (ITERS,384,20) fp32 -> ewb (ITERS,384,32) bf16, k>=20 zero-padded (MFMA B rows)
__global__ __launch_bounds__(256) void cvt_ew_kernel(const float* __restrict__ ew,
    u16* __restrict__ ewb)
{
    int idx = blockIdx.x * 256 + threadIdx.x;
    if (idx >= NITER * F3 * 32) return;
    int k = idx & 31;
    int row = idx >> 5;
    ewb[idx] = (k < RBFN) ? f2b(ew[row * RBFN + k]) : (u16)0;
}

// ---------------------------------------------------------------- elementwise
__global__ __launch_bounds__(256) void embed_kernel(const int* __restrict__ z,
    const float* __restrict__ emb, float* __restrict__ s, u16* __restrict__ sbf)
{
    int idx = blockIdx.x * 256 + threadIdx.x;
    if (idx >= NN * FD) return;
    int n = idx >> 7, f = idx & 127;
    float v = emb[z[n] * FD + f];
    s[idx] = v; sbf[idx] = f2b(v);
}

__global__ __launch_bounds__(256) void zero_f_kernel(float* __restrict__ p, int n)
{
    int idx = blockIdx.x * 256 + threadIdx.x;
    if (idx < n) p[idx] = 0.f;
}

__global__ __launch_bounds__(256) void zero_i_kernel(int* __restrict__ p, int n)
{
    int idx = blockIdx.x * 256 + threadIdx.x;
    if (idx < n) p[idx] = 0;
}

// ---------------------------------------------------------------- CSR build
__global__ __launch_bounds__(256) void csr_count_kernel(const int* __restrict__ graph,
    int* __restrict__ cnt)
{
    int e = blockIdx.x * 256 + threadIdx.x;
    if (e >= NE) return;
    atomicAdd(&cnt[graph[2 * e]], 1);
}

__global__ __launch_bounds__(1024) void csr_scan_kernel(const int* __restrict__ cnt,
    int* __restrict__ row_ptr, int* __restrict__ cursor)
{
    __shared__ int sd[1024];
    int tid = threadIdx.x;
    const int chunk = (NN + 1023) / 1024;
    int start = tid * chunk;
    int end = start + chunk; if (end > NN) end = NN;
    int sum = 0;
    for (int j = start; j < end; j++) sum += cnt[j];
    sd[tid] = sum;
    __syncthreads();
    for (int off = 1; off < 1024; off <<= 1) {
        int v = 0;
        if (tid >= off) v = sd[tid - off];
        __syncthreads();
        if (tid >= off) sd[tid] += v;
        __syncthreads();
    }
    int run = (tid == 0) ? 0 : sd[tid - 1];
    for (int j = start; j < end; j++) {
        row_ptr[j] = run;
        cursor[j]  = run;
        run += cnt[j];
    }
    if (tid == 0) row_ptr[NN] = NE;
}

__global__ __launch_bounds__(256) void csr_scatter_kernel(const int* __restrict__ graph,
    int* __restrict__ cursor, int* __restrict__ edge_list)
{
    int e = blockIdx.x * 256 + threadIdx.x;
    if (e >= NE) return;
    int p = atomicAdd(&cursor[graph[2 * e]], 1);
    edge_list[p] = e;
}

// Permuted edge streams in CSR order: rbf as bf16 MFMA-A rows (K=32 padded), cut/sense/dst
__global__ __launch_bounds__(256) void edge_stream_kernel(
    const int* __restrict__ edge_list, const int* __restrict__ graph,
    const float* __restrict__ dist, const float* __restrict__ sense,
    u16* __restrict__ rbf_bf, float* __restrict__ cut_p,
    float* __restrict__ sense_p, int* __restrict__ dst_p)
{
    int j = blockIdx.x * 256 + threadIdx.x;
    if (j >= NE) return;
    int e = edge_list[j];
    float d = dist[e];
    float inv = 1.f / d;
    float base = PI_ * d / RC_;
    u16* rb = rbf_bf + (size_t)j * 32;
    #pragma unroll
    for (int k = 0; k < RBFN; k++)
        rb[k] = f2b(sinf((float)(k + 1) * base) * inv);
    #pragma unroll
    for (int k = RBFN; k < 32; k++) rb[k] = 0;
    cut_p[j] = 0.5f * (cosf(base) + 1.f) * (d < RC_ ? 1.f : 0.f);
    dst_p[j] = graph[2 * e + 1];
    sense_p[3 * j + 0] = sense[3 * e + 0];
    sense_p[3 * j + 1] = sense[3 * e + 1];
    sense_p[3 * j + 2] = sense[3 * e + 2];
}

// ---------------------------------------------------------------- bf16 MFMA GEMM (final head)
template<bool SILU>
__global__ __launch_bounds__(256) void gemm_bf16(const u16* __restrict__ A,
    const u16* __restrict__ Wt, const float* __restrict__ bias,
    float* __restrict__ C, int M, int K, int Nc)
{
    __shared__ u16 As[64][KB + LPAD];
    __shared__ u16 Bs[64][KB + LPAD];
    const int bm = blockIdx.x * 64;
    const int bn = blockIdx.y * 64;
    const int tid = threadIdx.x;
    const int r = tid >> 2;
    const int q = tid & 3;
    const int wave = tid >> 6;
    const int lane = tid & 63;
    const int wm = (wave >> 1) * 32;
    const int wn = (wave & 1) * 32;
    const int quad = lane >> 4;
    const int lr = lane & 15;

    floatx4 acc[2][2];
    #pragma unroll
    for (int i = 0; i < 2; i++)
        #pragma unroll
        for (int j = 0; j < 2; j++)
            acc[i][j] = (floatx4)0.f;

    for (int ko = 0; ko < K; ko += KB) {
        {
            int gm = bm + r;
            u16* dA = &As[r][q * 32];
            if (gm < M) {
                const u16* ap = A + (size_t)gm * K + ko + q * 32;
                #pragma unroll
                for (int x = 0; x < 32; x += 8)
                    *(bf16x8*)&dA[x] = *(const bf16x8*)(ap + x);
            } else {
                #pragma unroll
                for (int x = 0; x < 32; x += 8)
                    *(bf16x8*)&dA[x] = (bf16x8)0;
            }
        }
        {
            int gn = bn + r;
            const u16* wp = Wt + (size_t)gn * K + ko + q * 32;
            u16* dB = &Bs[r][q * 32];
            #pragma unroll
            for (int x = 0; x < 32; x += 8)
                *(bf16x8*)&dB[x] = *(const bf16x8*)(wp + x);
        }
        __syncthreads();
        #pragma unroll
        for (int kk = 0; kk < KB; kk += 32) {
            bf16x8 a0 = *(const bf16x8*)&As[wm + lr     ][kk + quad * 8];
            bf16x8 a1 = *(const bf16x8*)&As[wm + 16 + lr][kk + quad * 8];
            bf16x8 b0 = *(const bf16x8*)&Bs[wn + lr     ][kk + quad * 8];
            bf16x8 b1 = *(const bf16x8*)&Bs[wn + 16 + lr][kk + quad * 8];
            acc[0][0] = __builtin_amdgcn_mfma_f32_16x16x32_bf16(a0, b0, acc[0][0], 0, 0, 0);
            acc[0][1] = __builtin_amdgcn_mfma_f32_16x16x32_bf16(a0, b1, acc[0][1], 0, 0, 0);
            acc[1][0] = __builtin_amdgcn_mfma_f32_16x16x32_bf16(a1, b0, acc[1][0], 0, 0, 0);
            acc[1][1] = __builtin_amdgcn_mfma_f32_16x16x32_bf16(a1, b1, acc[1][1], 0, 0, 0);
        }
        __syncthreads();
    }

    #pragma unroll
    for (int i = 0; i < 2; i++) {
        #pragma unroll
        for (int j = 0; j < 2; j++) {
            int gn = bn + wn + j * 16 + lr;
            float bb = bias ? bias[gn] : 0.f;
            #pragma unroll
            for (int rr = 0; rr < 4; rr++) {
                int gm = bm + wm + i * 16 + quad * 4 + rr;
                if (gm < M) {
                    float v = acc[i][j][rr] + bb;
                    if (SILU) v = v / (1.f + __expf(-v));
                    C[(size_t)gm * Nc + gn] = v;
                }
            }
        }
    }
}

// ---------------------------------------------------------------- fused node MLP
// Ob = (silu(A@W1^T + b1)) @ W2^T + b2.  A:(M,K1) bf16, W1:(128,K1), W2:(384,128).
// PACK: write Ob as ushort4-packed [gm][f][c] (c = gn>>7) for the edge gather.
template<int K1, bool PACK>
__global__ __launch_bounds__(256) void mlp_kernel(const u16* __restrict__ A,
    const u16* __restrict__ W1, const float* __restrict__ b1,
    const u16* __restrict__ W2, const float* __restrict__ b2,
    u16* __restrict__ Ob, int M)
{
    __shared__ u16 As[64][KB + LPAD];
    __shared__ u16 Ws[128][KB + LPAD];
    __shared__ u16 T[64][KB + LPAD];
    const int bm = blockIdx.x * 64;
    const int tid = threadIdx.x;
    const int wave = tid >> 6, lane = tid & 63;
    const int wm  = (wave >> 1) * 32;
    const int wn1 = (wave & 1) * 64;
    const int wn  = (wave & 1) * 32;
    const int quad = lane >> 4, lr = lane & 15;
    const int r = tid >> 2, q = tid & 3;

    floatx4 acc1[2][4];
    #pragma unroll
    for (int i = 0; i < 2; i++)
        #pragma unroll
        for (int j = 0; j < 4; j++) acc1[i][j] = (floatx4)0.f;

    for (int ko = 0; ko < K1; ko += KB) {
        {
            int gm = bm + r;
            u16* dA = &As[r][q * 32];
            if (gm < M) {
                const u16* ap = A + (size_t)gm * K1 + ko + q * 32;
                #pragma unroll
                for (int x = 0; x < 32; x += 8)
                    *(bf16x8*)&dA[x] = *(const bf16x8*)(ap + x);
            } else {
                #pragma unroll
                for (int x = 0; x < 32; x += 8)
                    *(bf16x8*)&dA[x] = (bf16x8)0;
            }
            #pragma unroll
            for (int h = 0; h < 2; h++) {
                int wr = r + h * 64;
                const u16* wp = W1 + (size_t)wr * K1 + ko + q * 32;
                u16* dW = &Ws[wr][q * 32];
                #pragma unroll
                for (int x = 0; x < 32; x += 8)
                    *(bf16x8*)&dW[x] = *(const bf16x8*)(wp + x);
            }
        }
        __syncthreads();
        #pragma unroll
        for (int kk = 0; kk < KB; kk += 32) {
            bf16x8 a0 = *(const bf16x8*)&As[wm + lr     ][kk + quad * 8];
            bf16x8 a1 = *(const bf16x8*)&As[wm + 16 + lr][kk + quad * 8];
            #pragma unroll
            for (int j = 0; j < 4; j++) {
                bf16x8 b = *(const bf16x8*)&Ws[wn1 + j * 16 + lr][kk + quad * 8];
                acc1[0][j] = __builtin_amdgcn_mfma_f32_16x16x32_bf16(a0, b, acc1[0][j], 0, 0, 0);
                acc1[1][j] = __builtin_amdgcn_mfma_f32_16x16x32_bf16(a1, b, acc1[1][j], 0, 0, 0);
            }
        }
        __syncthreads();
    }
    #pragma unroll
    for (int i = 0; i < 2; i++) {
        #pragma unroll
        for (int j = 0; j < 4; j++) {
            int col = wn1 + j * 16 + lr;
            float bb = b1[col];
            #pragma unroll
            for (int rr = 0; rr < 4; rr++) {
                int row = wm + i * 16 + quad * 4 + rr;
                float v = acc1[i][j][rr] + bb;
                v = v / (1.f + __expf(-v));
                T[row][col] = f2b(v);
            }
        }
    }
    __syncthreads();

    for (int c0 = 0; c0 < F3; c0 += 64) {
        {
            const u16* wp = W2 + (size_t)(c0 + r) * KB + q * 32;
            u16* dW = &Ws[r][q * 32];
            #pragma unroll
            for (int x = 0; x < 32; x += 8)
                *(bf16x8*)&dW[x] = *(const bf16x8*)(wp + x);
        }
        __syncthreads();
        floatx4 acc2[2][2];
        #pragma unroll
        for (int i = 0; i < 2; i++)
            #pragma unroll
            for (int j = 0; j < 2; j++) acc2[i][j] = (floatx4)0.f;
        #pragma unroll
        for (int kk = 0; kk < KB; kk += 32) {
            bf16x8 a0 = *(const bf16x8*)&T[wm + lr     ][kk + quad * 8];
            bf16x8 a1 = *(const bf16x8*)&T[wm + 16 + lr][kk + quad * 8];
            bf16x8 b0 = *(const bf16x8*)&Ws[wn + lr     ][kk + quad * 8];
            bf16x8 b1 = *(const bf16x8*)&Ws[wn + 16 + lr][kk + quad * 8];
            acc2[0][0] = __builtin_amdgcn_mfma_f32_16x16x32_bf16(a0, b0, acc2[0][0], 0, 0, 0);
            acc2[0][1] = __builtin_amdgcn_mfma_f32_16x16x32_bf16(a0, b1, acc2[0][1], 0, 0, 0);
            acc2[1][0] = __builtin_amdgcn_mfma_f32_16x16x32_bf16(a1, b0, acc2[1][0], 0, 0, 0);
            acc2[1][1] = __builtin_amdgcn_mfma_f32_16x16x32_bf16(a1, b1, acc2[1][1], 0, 0, 0);
        }
        #pragma unroll
        for (int i = 0; i < 2; i++) {
            #pragma unroll
            for (int j = 0; j < 2; j++) {
                int gn = c0 + wn + j * 16 + lr;
                float bb = b2[gn];
                #pragma unroll
                for (int rr = 0; rr < 4; rr++) {
                    int gm = bm + wm + i * 16 + quad * 4 + rr;
                    if (gm < M) {
                        u16 val = f2b(acc2[i][j][rr] + bb);
                        if (PACK)
                            Ob[(size_t)gm * 512 + (gn & 127) * 4 + (gn >> 7)] = val;
                        else
                            Ob[(size_t)gm * F3 + gn] = val;
                    }
                }
            }
        }
        __syncthreads();
    }
}

// Dual GEMM: U = A@Wu^T, V = A@Wv^T (K=128, Nc=128). bf16 outs.
__global__ __launch_bounds__(256) void gemm_uv(const u16* __restrict__ A,
    const u16* __restrict__ Wu, const u16* __restrict__ Wv,
    u16* __restrict__ U, u16* __restrict__ V, int M)
{
    __shared__ u16 As[64][KB + LPAD];
    __shared__ u16 Bu[64][KB + LPAD];
    __shared__ u16 Bv[64][KB + LPAD];
    const int bm = blockIdx.x * 64;
    const int bn = blockIdx.y * 64;
    const int tid = threadIdx.x;
    const int r = tid >> 2;
    const int q = tid & 3;
    const int wave = tid >> 6;
    const int lane = tid & 63;
    const int wm = (wave >> 1) * 32;
    const int wn = (wave & 1) * 32;
    const int quad = lane >> 4;
    const int lr = lane & 15;

    floatx4 au[2][2], av[2][2];
    #pragma unroll
    for (int i = 0; i < 2; i++)
        #pragma unroll
        for (int j = 0; j < 2; j++) { au[i][j] = (floatx4)0.f; av[i][j] = (floatx4)0.f; }

    {
        int gm = bm + r;
        u16* dA = &As[r][q * 32];
        if (gm < M) {
            const u16* ap = A + (size_t)gm * KB + q * 32;
            #pragma unroll
            for (int x = 0; x < 32; x += 8)
                *(bf16x8*)&dA[x] = *(const bf16x8*)(ap + x);
        } else {
            #pragma unroll
            for (int x = 0; x < 32; x += 8)
                *(bf16x8*)&dA[x] = (bf16x8)0;
        }
        int gn = bn + r;
        const u16* up = Wu + (size_t)gn * KB + q * 32;
        const u16* vp = Wv + (size_t)gn * KB + q * 32;
        u16* dU = &Bu[r][q * 32];
        u16* dV = &Bv[r][q * 32];
        #pragma unroll
        for (int x = 0; x < 32; x += 8) {
            *(bf16x8*)&dU[x] = *(const bf16x8*)(up + x);
            *(bf16x8*)&dV[x] = *(const bf16x8*)(vp + x);
        }
    }
    __syncthreads();
    #pragma unroll
    for (int kk = 0; kk < KB; kk += 32) {
        bf16x8 a0 = *(const bf16x8*)&As[wm + lr     ][kk + quad * 8];
        bf16x8 a1 = *(const bf16x8*)&As[wm + 16 + lr][kk + quad * 8];
        bf16x8 u0 = *(const bf16x8*)&Bu[wn + lr     ][kk + quad * 8];
        bf16x8 u1 = *(const bf16x8*)&Bu[wn + 16 + lr][kk + quad * 8];
        bf16x8 v0 = *(const bf16x8*)&Bv[wn + lr     ][kk + quad * 8];
        bf16x8 v1 = *(const bf16x8*)&Bv[wn + 16 + lr][kk + quad * 8];
        au[0][0] = __builtin_amdgcn_mfma_f32_16x16x32_bf16(a0, u0, au[0][0], 0, 0, 0);
        au[0][1] = __builtin_amdgcn_mfma_f32_16x16x32_bf16(a0, u1, au[0][1], 0, 0, 0);
        au[1][0] = __builtin_amdgcn_mfma_f32_16x16x32_bf16(a1, u0, au[1][0], 0, 0, 0);
        au[1][1] = __builtin_amdgcn_mfma_f32_16x16x32_bf16(a1, u1, au[1][1], 0, 0, 0);
        av[0][0] = __builtin_amdgcn_mfma_f32_16x16x32_bf16(a0, v0, av[0][0], 0, 0, 0);
        av[0][1] = __builtin_amdgcn_mfma_f32_16x16x32_bf16(a0, v1, av[0][1], 0, 0, 0);
        av[1][0] = __builtin_amdgcn_mfma_f32_16x16x32_bf16(a1, v0, av[1][0], 0, 0, 0);
        av[1][1] = __builtin_amdgcn_mfma_f32_16x16x32_bf16(a1, v1, av[1][1], 0, 0, 0);
    }
    #pragma unroll
    for (int i = 0; i < 2; i++) {
        #pragma unroll
        for (int j = 0; j < 2; j++) {
            int gn = bn + wn + j * 16 + lr;
            #pragma unroll
            for (int rr = 0; rr < 4; rr++) {
                int gm = bm + wm + i * 16 + quad * 4 + rr;
                if (gm < M) {
                    U[(size_t)gm * FD + gn] = f2b(au[i][j][rr]);
                    V[(size_t)gm * FD + gn] = f2b(av[i][j][rr]);
                }
            }
        }
    }
}

// ---------------------------------------------------------------- edge aggregate (MFMA dist_rep, packed gathers)
__global__ __launch_bounds__(256) void edge_mfma_kernel(
    const u16* __restrict__ rbf_bf, const float* __restrict__ cut_p,
    const float* __restrict__ sense_p, const int* __restrict__ dst_p,
    const u16* __restrict__ ewb, const float* __restrict__ eb,
    const u16* __restrict__ a_pk, const float* __restrict__ s_in,
    const float* __restrict__ v_in, const u16* __restrict__ v_pk,
    const int* __restrict__ row_ptr,
    float* __restrict__ s_out, u16* __restrict__ s_obf,
    float* __restrict__ v_out, u16* __restrict__ v_obf)
{
    __shared__ u16   sdrep[16 * SD_STRIDE];   // bf16 (drv,drs,drd,pad) per (edge,f) — 16.5 KB
    __shared__ float scut[16];
    __shared__ float ssen[16][4];
    __shared__ int   sdst[16];
    __shared__ float red[4 * 128];

    const int n = blockIdx.x;
    const int tid = threadIdx.x;
    const int wave = tid >> 6;
    const int lane = tid & 63;
    const int quad = lane >> 4;
    const int lr = lane & 15;
    const int f = tid & 127;
    const int half = tid >> 7;

    int beg = row_ptr[n], end = row_ptr[n + 1];
    float accs = 0.f, accv0 = 0.f, accv1 = 0.f, accv2 = 0.f;

    for (int t0 = beg; t0 < end; t0 += 16) {
        int cnt = end - t0; if (cnt > 16) cnt = 16;
        __syncthreads();   // previous tile fully consumed
        if (tid < 16) {
            scut[tid] = (tid < cnt) ? cut_p[t0 + tid] : 0.f;
            sdst[tid] = (tid < cnt) ? dst_p[t0 + tid] : 0;
        }
        if (tid >= 64 && tid < 64 + 3 * cnt) {
            int x = tid - 64;
            ssen[x / 3][x % 3] = sense_p[3 * t0 + x];
        }
        // MFMA: A = rbf rows (lane m=lr = edge), B = ew rows (6 col-tiles/wave)
        bf16x8 afrag;
        int ge = t0 + lr;
        if (ge < end) afrag = *(const bf16x8*)&rbf_bf[(size_t)ge * 32 + quad * 8];
        else          afrag = (bf16x8)0;
        floatx4 dacc[6];
        #pragma unroll
        for (int nt = 0; nt < 6; nt++) {
            int nrow = (wave * 6 + nt) * 16 + lr;
            bf16x8 bfrag = *(const bf16x8*)&ewb[(size_t)nrow * 32 + quad * 8];
            dacc[nt] = __builtin_amdgcn_mfma_f32_16x16x32_bf16(afrag, bfrag, (floatx4)0.f, 0, 0, 0);
        }
        __syncthreads();   // staged scalars visible
        // epilogue: (d + eb) * cut -> bf16 packed sdrep[e][f][c]
        #pragma unroll
        for (int nt = 0; nt < 6; nt++) {
            int ncol = (wave * 6 + nt) * 16 + lr;
            int fc = ncol & 127, c = ncol >> 7;
            float ebn = eb[ncol];
            #pragma unroll
            for (int rr = 0; rr < 4; rr++) {
                int e = quad * 4 + rr;
                sdrep[e * SD_STRIDE + fc * 4 + c] = f2b((dacc[nt][rr] + ebn) * scut[e]);
            }
        }
        __syncthreads();   // sdrep ready
        // aggregation: half h handles up to 8 edges
        int nh = cnt - half * 8; if (nh > 8) nh = 8;
        for (int k = 0; k < nh; k++) {
            int e = half * 8 + k;
            int dst = sdst[e];
            ushort4 dr = *(const ushort4*)&sdrep[e * SD_STRIDE + f * 4];
            float drv = b2f(dr.x), drs = b2f(dr.y), drd = b2f(dr.z);
            ushort4 a4 = *(const ushort4*)(a_pk + (size_t)dst * 512 + f * 4);
            float rv = b2f(a4.x) * drv;
            float rs = b2f(a4.y) * drs;
            float rd = b2f(a4.z) * drd;
            accs += rs;
            ushort4 v4 = *(const ushort4*)(v_pk + (size_t)dst * 512 + f * 4);
            accv0 += b2f(v4.x) * rv + ssen[e][0] * rd;
            accv1 += b2f(v4.y) * rv + ssen[e][1] * rd;
            accv2 += b2f(v4.z) * rv + ssen[e][2] * rd;
        }
    }
    // combine halves, write
    __syncthreads();
    if (half == 1) {
        red[f] = accs; red[128 + f] = accv0; red[256 + f] = accv1; red[384 + f] = accv2;
    }
    __syncthreads();
    if (half == 0) {
        accs  += red[f];       accv0 += red[128 + f];
        accv1 += red[256 + f]; accv2 += red[384 + f];
        int nb = n * FD + f;
        float so = s_in[nb] + 2.f * accs;
        s_out[nb] = so; s_obf[nb] = f2b(so);
        int vb = n * F3 + f;
        float w0 = v_in[vb]           + 2.f * accv0;
        float w1 = v_in[vb + FD]      + 2.f * accv1;
        float w2 = v_in[vb + 2 * FD]  + 2.f * accv2;
        v_out[vb]          = w0; v_obf[vb]          = f2b(w0);
        v_out[vb + FD]     = w1; v_obf[vb + FD]     = f2b(w1);
        v_out[vb + 2 * FD] = w2; v_obf[vb + 2 * FD] = f2b(w2);
    }
}

// ---------------------------------------------------------------- h build (bf16): [s, |Vv|]
__global__ __launch_bounds__(256) void build_h_kernel(const u16* __restrict__ sbf,
    const u16* __restrict__ Vv, u16* __restrict__ h)
{
    int idx = blockIdx.x * 256 + threadIdx.x;
    if (idx >= NN * FD) return;
    int n = idx >> 7, f = idx & 127;
    h[n * F2 + f] = sbf[idx];
    float x0 = b2f(Vv[n * F3 + f]);
    float x1 = b2f(Vv[n * F3 + FD + f]);
    float x2 = b2f(Vv[n * F3 + 2 * FD + f]);
    h[n * F2 + FD + f] = f2b(sqrtf(x0 * x0 + x1 * x1 + x2 * x2));
}

// ---------------------------------------------------------------- node update
__global__ __launch_bounds__(256) void update_kernel(const float* __restrict__ s_mid,
    const float* __restrict__ v_mid, const u16* __restrict__ a2,
    const u16* __restrict__ Uv, const u16* __restrict__ Vv,
    float* __restrict__ s_out, u16* __restrict__ s_obf,
    float* __restrict__ v_out, u16* __restrict__ v_pk)
{
    int idx = blockIdx.x * 256 + threadIdx.x;
    if (idx >= NN * FD) return;
    int n = idx >> 7, f = idx & 127;
    int vb = n * F3 + f;
    float u0 = b2f(Uv[vb]), u1 = b2f(Uv[vb + FD]), u2 = b2f(Uv[vb + 2 * FD]);
    float w0 = b2f(Vv[vb]), w1 = b2f(Vv[vb + FD]), w2 = b2f(Vv[vb + 2 * FD]);
    float dot = u0 * w0 + u1 * w1 + u2 * w2;
    float avv = b2f(a2[n * F3 + f]);
    float asv = b2f(a2[n * F3 + FD + f]);
    float ass = b2f(a2[n * F3 + 2 * FD + f]);
    float so = s_mid[idx] + ass + asv * dot;
    s_out[idx] = so; s_obf[idx] = f2b(so);
    float y0 = v_mid[vb]          + avv * u0;
    float y1 = v_mid[vb + FD]     + avv * u1;
    float y2 = v_mid[vb + 2 * FD] + avv * u2;
    v_out[vb]          = y0;
    v_out[vb + FD]     = y1;
    v_out[vb + 2 * FD] = y2;
    ushort4 pk; pk.x = f2b(y0); pk.y = f2b(y1); pk.z = f2b(y2); pk.w = 0;
    *(ushort4*)(v_pk + (size_t)idx * 4) = pk;
}

// ---------------------------------------------------------------- final head reduce (no atomics)
__global__ __launch_bounds__(256) void node_out_kernel(const float* __restrict__ t,
    const float* __restrict__ ow2, const float* __restrict__ ob2,
    float* __restrict__ nodeval)
{
    int gt = blockIdx.x * 256 + threadIdx.x;
    int n = gt >> 6;
    int lane = threadIdx.x & 63;
    if (n >= NN) return;
    float v = t[n * FD + lane] * ow2[lane] + t[n * FD + 64 + lane] * ow2[64 + lane];
    #pragma unroll
    for (int off = 32; off > 0; off >>= 1) v += __shfl_down(v, off);
    if (lane == 0) nodeval[n] = v + ob2[0];
}

__global__ __launch_bounds__(1024) void mol_reduce_kernel(const float* __restrict__ nodeval,
    const int* __restrict__ gidx, float* __restrict__ out)
{
    __shared__ float mol[NMOL];
    int tid = threadIdx.x;
    if (tid < NMOL) mol[tid] = 0.f;
    __syncthreads();
    int cur = -1; float acc = 0.f;
    for (int x = tid; x < NN; x += 1024) {
        int g = gidx[x];
        float v = nodeval[x];
        if (g != cur) {
            if (cur >= 0) atomicAdd(&mol[cur], acc);
            cur = g; acc = v;
        } else acc += v;
    }
    if (cur >= 0) atomicAdd(&mol[cur], acc);
    __syncthreads();
    if (tid < NMOL) out[tid] = mol[tid];
}

// ---------------------------------------------------------------- launch
extern "C" void kernel_launch(void* const* d_in, const int* in_sizes, int n_in,
                              void* d_out, int out_size, void* d_ws, size_t ws_size,
                              hipStream_t stream)
{
    const int*   z     = (const int*)d_in[0];
    const int*   graph = (const int*)d_in[1];
    const float* dist  = (const float*)d_in[2];
    const float* sense = (const float*)d_in[3];
    const int*   gidx  = (const int*)d_in[4];
    const float* emb   = (const float*)d_in[5];
    const float* mw1   = (const float*)d_in[6];
    const float* mb1   = (const float*)d_in[7];
    const float* mw2   = (const float*)d_in[8];
    const float* mb2   = (const float*)d_in[9];
    const float* ew    = (const float*)d_in[10];
    const float* eb    = (const float*)d_in[11];
    const float* uw    = (const float*)d_in[12];
    const float* vw    = (const float*)d_in[13];
    const float* aw1   = (const float*)d_in[14];
    const float* ab1   = (const float*)d_in[15];
    const float* aw2   = (const float*)d_in[16];
    const float* ab2   = (const float*)d_in[17];
    const float* ow1   = (const float*)d_in[18];
    const float* ob1   = (const float*)d_in[19];
    const float* ow2   = (const float*)d_in[20];
    const float* ob2   = (const float*)d_in[21];
    float* out = (float*)d_out;

    // ---- workspace carve-up (~237 MB) ----
    float* W = (float*)d_ws;
    float* s_a    = W; W += (size_t)NN * FD;
    float* s_b    = W; W += (size_t)NN * FD;     // also aliased as tfin after last iter
    float* v_a    = W; W += (size_t)NN * F3;
    float* v_b    = W; W += (size_t)NN * F3;
    float* cut_p  = W; W += (size_t)NE;
    float* sns_p  = W; W += (size_t)NE * 3;
    float* nodeval= W; W += (size_t)NN;
    u16* U = (u16*)W;
    u16* sbf_a = U; U += (size_t)NN * FD;
    u16* sbf_b = U; U += (size_t)NN * FD;
    u16* vbf_b = U; U += (size_t)NN * F3;
    u16* a_pk  = U; U += (size_t)NN * 512;
    u16* v_pk  = U; U += (size_t)NN * 512;
    u16* h_bf  = U; U += (size_t)NN * F2;
    u16* a2_bf = U; U += (size_t)NN * F3;
    u16* Uv_bf = U; U += (size_t)NN * F3;
    u16* Vv_bf = U; U += (size_t)NN * F3;
    u16* rbf_bf= U; U += (size_t)NE * 32;
    u16* ewb   = U; U += (size_t)NITER * F3 * 32;
    u16* wb    = U; U += 557056;
    int* ip = (int*)U;
    int* row_ptr   = ip; ip += NN + 1;
    int* cnt       = ip; ip += NN;
    int* cursor    = ip; ip += NN;
    int* edge_list = ip; ip += NE;
    int* dst_p     = ip; ip += NE;
    float* tfin = s_b;

    // bf16 weight table offsets
    u16* wb_mw1 = wb;            // 3*128*128
    u16* wb_mw2 = wb + 49152;    // 3*384*128
    u16* wb_uw  = wb + 196608;   // 3*128*128
    u16* wb_vw  = wb + 245760;   // 3*128*128
    u16* wb_aw1 = wb + 294912;   // 3*128*256
    u16* wb_aw2 = wb + 393216;   // 3*384*128
    u16* wb_ow1 = wb + 540672;   // 128*128
    const int WTOT = 557056;

    const int TB = 256;
    dim3 b256(TB);

    // --- precompute ---
    cvt_w_kernel<<<dim3((WTOT + TB - 1) / TB), b256, 0, stream>>>(
        mw1, 49152, mw2, 147456, uw, 49152, vw, 49152, aw1, 98304, aw2, 147456,
        ow1, 16384, wb);
    cvt_ew_kernel<<<dim3((NITER * F3 * 32 + TB - 1) / TB), b256, 0, stream>>>(ew, ewb);
    embed_kernel<<<dim3((NN * FD + TB - 1) / TB), b256, 0, stream>>>(z, emb, s_a, sbf_a);
    zero_f_kernel<<<dim3((NN * F3 + TB - 1) / TB), b256, 0, stream>>>(v_a, NN * F3);
    zero_i_kernel<<<dim3((NN * 256 + TB - 1) / TB), b256, 0, stream>>>((int*)v_pk, NN * 256);
    zero_i_kernel<<<dim3((NN + TB - 1) / TB), b256, 0, stream>>>(cnt, NN);
    csr_count_kernel<<<dim3((NE + TB - 1) / TB), b256, 0, stream>>>(graph, cnt);
    csr_scan_kernel<<<dim3(1), dim3(1024), 0, stream>>>(cnt, row_ptr, cursor);
    csr_scatter_kernel<<<dim3((NE + TB - 1) / TB), b256, 0, stream>>>(graph, cursor, edge_list);
    edge_stream_kernel<<<dim3((NE + TB - 1) / TB), b256, 0, stream>>>(
        edge_list, graph, dist, sense, rbf_bf, cut_p, sns_p, dst_p);

    dim3 gM((NN + 63) / 64);                   // fused MLPs
    dim3 gN2((NN + 63) / 64, FD / 64);         // final head
    dim3 gV2((3 * NN + 63) / 64, FD / 64);     // M=3N, Nc=128

    for (int i = 0; i < NITER; i++) {
        mlp_kernel<128, true><<<gM, b256, 0, stream>>>(sbf_a,
            wb_mw1 + (size_t)i * FD * FD, mb1 + (size_t)i * FD,
            wb_mw2 + (size_t)i * F3 * FD, mb2 + (size_t)i * F3, a_pk, NN);
        edge_mfma_kernel<<<dim3(NN), b256, 0, stream>>>(
            rbf_bf, cut_p, sns_p, dst_p,
            ewb + (size_t)i * F3 * 32, eb + (size_t)i * F3,
            a_pk, s_a, v_a, v_pk, row_ptr, s_b, sbf_b, v_b, vbf_b);
        gemm_uv<<<gV2, b256, 0, stream>>>(vbf_b, wb_uw + (size_t)i * FD * FD,
            wb_vw + (size_t)i * FD * FD, Uv_bf, Vv_bf, 3 * NN);
        build_h_kernel<<<dim3((NN * FD + TB - 1) / TB), b256, 0, stream>>>(sbf_b, Vv_bf, h_bf);
        mlp_kernel<256, false><<<gM, b256, 0, stream>>>(h_bf,
            wb_aw1 + (size_t)i * FD * F2, ab1 + (size_t)i * FD,
            wb_aw2 + (size_t)i * F3 * FD, ab2 + (size_t)i * F3, a2_bf, NN);
        update_kernel<<<dim3((NN * FD + TB - 1) / TB), b256, 0, stream>>>(
            s_b, v_b, a2_bf, Uv_bf, Vv_bf, s_a, sbf_a, v_a, v_pk);
    }

    gemm_bf16<true><<<gN2, b256, 0, stream>>>(sbf_a, wb_ow1, ob1, tfin, NN, FD, FD);
    node_out_kernel<<<dim3((NN * 64 + TB - 1) / TB), b256, 0, stream>>>(tfin, ow2, ob2, nodeval);
    mol_reduce_kernel<<<dim3(1), dim3(1024), 0, stream>>>(nodeval, gidx, out);
}

// Round 7
// 948.897 us; speedup vs baseline: 1.0505x; 1.0505x over previous
//
#include <hip/hip_runtime.h>
#include <math.h>

// Problem constants
#define NN 20000
#define NE 320000
#define FD 128
#define RBFN 20
#define RC_ 5.0f
#define NITER 3
#define NMOL 64
#define F3 384
#define F2 256
#define PI_ 3.14159265358979323846f
#define KB 128
#define LPAD 8
#define SDS 392   // u16 stride per sdrep edge row (384 + 8 pad)

typedef __attribute__((ext_vector_type(8))) short  bf16x8;
typedef __attribute__((ext_vector_type(4))) float  floatx4;
typedef unsigned short u16;
typedef unsigned int   u32;

__device__ __forceinline__ u16 f2b(float x) {
    union { float f; unsigned int u; } v; v.f = x;
    unsigned int u = v.u;
    return (u16)((u + 0x7fffu + ((u >> 16) & 1u)) >> 16);   // RNE
}
__device__ __forceinline__ float b2f(u16 x) {
    union { unsigned int u; float f; } v; v.u = ((unsigned int)x) << 16;
    return v.f;
}

// ---------------------------------------------------------------- weight cvt (once per launch)
__global__ __launch_bounds__(256) void cvt_w_kernel(
    const float* s0, int n0, const float* s1, int n1, const float* s2, int n2,
    const float* s3, int n3, const float* s4, int n4, const float* s5, int n5,
    const float* s6, int n6, u16* __restrict__ dst)
{
    int idx = blockIdx.x * 256 + threadIdx.x;
    if (idx < n0) { dst[idx] = f2b(s0[idx]); return; } idx -= n0; dst += n0;
    if (idx < n1) { dst[idx] = f2b(s1[idx]); return; } idx -= n1; dst += n1;
    if (idx < n2) { dst[idx] = f2b(s2[idx]); return; } idx -= n2; dst += n2;
    if (idx < n3) { dst[idx] = f2b(s3[idx]); return; } idx -= n3; dst += n3;
    if (idx < n4) { dst[idx] = f2b(s4[idx]); return; } idx -= n4; dst += n4;
    if (idx < n5) { dst[idx] = f2b(s5[idx]); return; } idx -= n5; dst += n5;
    if (idx < n6) { dst[idx] = f2b(s6[idx]); }
}

// ew (ITERS,384,20) fp32 -> ewb (ITERS,384,32) bf16, k>=20 zero-padded (MFMA B rows)
__global__ __launch_bounds__(256) void cvt_ew_kernel(const float* __restrict__ ew,
    u16* __restrict__ ewb)
{
    int idx = blockIdx.x * 256 + threadIdx.x;
    if (idx >= NITER * F3 * 32) return;
    int k = idx & 31;
    int row = idx >> 5;
    ewb[idx] = (k < RBFN) ? f2b(ew[row * RBFN + k]) : (u16)0;
}

// ---------------------------------------------------------------- elementwise
__global__ __launch_bounds__(256) void embed_kernel(const int* __restrict__ z,
    const float* __restrict__ emb, float* __restrict__ s, u16* __restrict__ sbf)
{
    int idx = blockIdx.x * 256 + threadIdx.x;
    if (idx >= NN * FD) return;
    int n = idx >> 7, f = idx & 127;
    float v = emb[z[n] * FD + f];
    s[idx] = v; sbf[idx] = f2b(v);
}

__global__ __launch_bounds__(256) void zero_f_kernel(float* __restrict__ p, int n)
{
    int idx = blockIdx.x * 256 + threadIdx.x;
    if (idx < n) p[idx] = 0.f;
}

__global__ __launch_bounds__(256) void zero_i_kernel(int* __restrict__ p, int n)
{
    int idx = blockIdx.x * 256 + threadIdx.x;
    if (idx < n) p[idx] = 0;
}

// ---------------------------------------------------------------- CSR build
__global__ __launch_bounds__(256) void csr_count_kernel(const int* __restrict__ graph,
    int* __restrict__ cnt)
{
    int e = blockIdx.x * 256 + threadIdx.x;
    if (e >= NE) return;
    atomicAdd(&cnt[graph[2 * e]], 1);
}

__global__ __launch_bounds__(1024) void csr_scan_kernel(const int* __restrict__ cnt,
    int* __restrict__ row_ptr, int* __restrict__ cursor)
{
    __shared__ int sd[1024];
    int tid = threadIdx.x;
    const int chunk = (NN + 1023) / 1024;
    int start = tid * chunk;
    int end = start + chunk; if (end > NN) end = NN;
    int sum = 0;
    for (int j = start; j < end; j++) sum += cnt[j];
    sd[tid] = sum;
    __syncthreads();
    for (int off = 1; off < 1024; off <<= 1) {
        int v = 0;
        if (tid >= off) v = sd[tid - off];
        __syncthreads();
        if (tid >= off) sd[tid] += v;
        __syncthreads();
    }
    int run = (tid == 0) ? 0 : sd[tid - 1];
    for (int j = start; j < end; j++) {
        row_ptr[j] = run;
        cursor[j]  = run;
        run += cnt[j];
    }
    if (tid == 0) row_ptr[NN] = NE;
}

__global__ __launch_bounds__(256) void csr_scatter_kernel(const int* __restrict__ graph,
    int* __restrict__ cursor, int* __restrict__ edge_list)
{
    int e = blockIdx.x * 256 + threadIdx.x;
    if (e >= NE) return;
    int p = atomicAdd(&cursor[graph[2 * e]], 1);
    edge_list[p] = e;
}

// Permuted edge streams in CSR order: rbf as bf16 MFMA-A rows (K=32 padded), cut/sense/dst
__global__ __launch_bounds__(256) void edge_stream_kernel(
    const int* __restrict__ edge_list, const int* __restrict__ graph,
    const float* __restrict__ dist, const float* __restrict__ sense,
    u16* __restrict__ rbf_bf, float* __restrict__ cut_p,
    float* __restrict__ sense_p, int* __restrict__ dst_p)
{
    int j = blockIdx.x * 256 + threadIdx.x;
    if (j >= NE) return;
    int e = edge_list[j];
    float d = dist[e];
    float inv = 1.f / d;
    float base = PI_ * d / RC_;
    u16* rb = rbf_bf + (size_t)j * 32;
    #pragma unroll
    for (int k = 0; k < RBFN; k++)
        rb[k] = f2b(sinf((float)(k + 1) * base) * inv);
    #pragma unroll
    for (int k = RBFN; k < 32; k++) rb[k] = 0;
    cut_p[j] = 0.5f * (cosf(base) + 1.f) * (d < RC_ ? 1.f : 0.f);
    dst_p[j] = graph[2 * e + 1];
    sense_p[3 * j + 0] = sense[3 * e + 0];
    sense_p[3 * j + 1] = sense[3 * e + 1];
    sense_p[3 * j + 2] = sense[3 * e + 2];
}

// ---------------------------------------------------------------- bf16 MFMA GEMM (final head)
template<bool SILU>
__global__ __launch_bounds__(256) void gemm_bf16(const u16* __restrict__ A,
    const u16* __restrict__ Wt, const float* __restrict__ bias,
    float* __restrict__ C, int M, int K, int Nc)
{
    __shared__ u16 As[64][KB + LPAD];
    __shared__ u16 Bs[64][KB + LPAD];
    const int bm = blockIdx.x * 64;
    const int bn = blockIdx.y * 64;
    const int tid = threadIdx.x;
    const int r = tid >> 2;
    const int q = tid & 3;
    const int wave = tid >> 6;
    const int lane = tid & 63;
    const int wm = (wave >> 1) * 32;
    const int wn = (wave & 1) * 32;
    const int quad = lane >> 4;
    const int lr = lane & 15;

    floatx4 acc[2][2];
    #pragma unroll
    for (int i = 0; i < 2; i++)
        #pragma unroll
        for (int j = 0; j < 2; j++)
            acc[i][j] = (floatx4)0.f;

    for (int ko = 0; ko < K; ko += KB) {
        {
            int gm = bm + r;
            u16* dA = &As[r][q * 32];
            if (gm < M) {
                const u16* ap = A + (size_t)gm * K + ko + q * 32;
                #pragma unroll
                for (int x = 0; x < 32; x += 8)
                    *(bf16x8*)&dA[x] = *(const bf16x8*)(ap + x);
            } else {
                #pragma unroll
                for (int x = 0; x < 32; x += 8)
                    *(bf16x8*)&dA[x] = (bf16x8)0;
            }
        }
        {
            int gn = bn + r;
            const u16* wp = Wt + (size_t)gn * K + ko + q * 32;
            u16* dB = &Bs[r][q * 32];
            #pragma unroll
            for (int x = 0; x < 32; x += 8)
                *(bf16x8*)&dB[x] = *(const bf16x8*)(wp + x);
        }
        __syncthreads();
        #pragma unroll
        for (int kk = 0; kk < KB; kk += 32) {
            bf16x8 a0 = *(const bf16x8*)&As[wm + lr     ][kk + quad * 8];
            bf16x8 a1 = *(const bf16x8*)&As[wm + 16 + lr][kk + quad * 8];
            bf16x8 b0 = *(const bf16x8*)&Bs[wn + lr     ][kk + quad * 8];
            bf16x8 b1 = *(const bf16x8*)&Bs[wn + 16 + lr][kk + quad * 8];
            acc[0][0] = __builtin_amdgcn_mfma_f32_16x16x32_bf16(a0, b0, acc[0][0], 0, 0, 0);
            acc[0][1] = __builtin_amdgcn_mfma_f32_16x16x32_bf16(a0, b1, acc[0][1], 0, 0, 0);
            acc[1][0] = __builtin_amdgcn_mfma_f32_16x16x32_bf16(a1, b0, acc[1][0], 0, 0, 0);
            acc[1][1] = __builtin_amdgcn_mfma_f32_16x16x32_bf16(a1, b1, acc[1][1], 0, 0, 0);
        }
        __syncthreads();
    }

    #pragma unroll
    for (int i = 0; i < 2; i++) {
        #pragma unroll
        for (int j = 0; j < 2; j++) {
            int gn = bn + wn + j * 16 + lr;
            float bb = bias ? bias[gn] : 0.f;
            #pragma unroll
            for (int rr = 0; rr < 4; rr++) {
                int gm = bm + wm + i * 16 + quad * 4 + rr;
                if (gm < M) {
                    float v = acc[i][j][rr] + bb;
                    if (SILU) v = v / (1.f + __expf(-v));
                    C[(size_t)gm * Nc + gn] = v;
                }
            }
        }
    }
}

// ---------------------------------------------------------------- fused node MLP
// Ob = (silu(A@W1^T + b1)) @ W2^T + b2.  A:(M,K1) bf16, W1:(128,K1), W2:(384,128).
// PACK layout (for edge gather): row of 384 u16 per node:
//   [0..255]  = (comp0, comp1) interleaved at f*2 + c   (c = gn>>7 for gn<256)
//   [256..383]= comp2 planar at 256 + (gn&127)
template<int K1, bool PACK>
__global__ __launch_bounds__(256) void mlp_kernel(const u16* __restrict__ A,
    const u16* __restrict__ W1, const float* __restrict__ b1,
    const u16* __restrict__ W2, const float* __restrict__ b2,
    u16* __restrict__ Ob, int M)
{
    __shared__ u16 As[64][KB + LPAD];
    __shared__ u16 Ws[128][KB + LPAD];
    __shared__ u16 T[64][KB + LPAD];
    const int bm = blockIdx.x * 64;
    const int tid = threadIdx.x;
    const int wave = tid >> 6, lane = tid & 63;
    const int wm  = (wave >> 1) * 32;
    const int wn1 = (wave & 1) * 64;
    const int wn  = (wave & 1) * 32;
    const int quad = lane >> 4, lr = lane & 15;
    const int r = tid >> 2, q = tid & 3;

    floatx4 acc1[2][4];
    #pragma unroll
    for (int i = 0; i < 2; i++)
        #pragma unroll
        for (int j = 0; j < 4; j++) acc1[i][j] = (floatx4)0.f;

    for (int ko = 0; ko < K1; ko += KB) {
        {
            int gm = bm + r;
            u16* dA = &As[r][q * 32];
            if (gm < M) {
                const u16* ap = A + (size_t)gm * K1 + ko + q * 32;
                #pragma unroll
                for (int x = 0; x < 32; x += 8)
                    *(bf16x8*)&dA[x] = *(const bf16x8*)(ap + x);
            } else {
                #pragma unroll
                for (int x = 0; x < 32; x += 8)
                    *(bf16x8*)&dA[x] = (bf16x8)0;
            }
            #pragma unroll
            for (int h = 0; h < 2; h++) {
                int wr = r + h * 64;
                const u16* wp = W1 + (size_t)wr * K1 + ko + q * 32;
                u16* dW = &Ws[wr][q * 32];
                #pragma unroll
                for (int x = 0; x < 32; x += 8)
                    *(bf16x8*)&dW[x] = *(const bf16x8*)(wp + x);
            }
        }
        __syncthreads();
        #pragma unroll
        for (int kk = 0; kk < KB; kk += 32) {
            bf16x8 a0 = *(const bf16x8*)&As[wm + lr     ][kk + quad * 8];
            bf16x8 a1 = *(const bf16x8*)&As[wm + 16 + lr][kk + quad * 8];
            #pragma unroll
            for (int j = 0; j < 4; j++) {
                bf16x8 b = *(const bf16x8*)&Ws[wn1 + j * 16 + lr][kk + quad * 8];
                acc1[0][j] = __builtin_amdgcn_mfma_f32_16x16x32_bf16(a0, b, acc1[0][j], 0, 0, 0);
                acc1[1][j] = __builtin_amdgcn_mfma_f32_16x16x32_bf16(a1, b, acc1[1][j], 0, 0, 0);
            }
        }
        __syncthreads();
    }
    #pragma unroll
    for (int i = 0; i < 2; i++) {
        #pragma unroll
        for (int j = 0; j < 4; j++) {
            int col = wn1 + j * 16 + lr;
            float bb = b1[col];
            #pragma unroll
            for (int rr = 0; rr < 4; rr++) {
                int row = wm + i * 16 + quad * 4 + rr;
                float v = acc1[i][j][rr] + bb;
                v = v / (1.f + __expf(-v));
                T[row][col] = f2b(v);
            }
        }
    }
    __syncthreads();

    for (int c0 = 0; c0 < F3; c0 += 64) {
        {
            const u16* wp = W2 + (size_t)(c0 + r) * KB + q * 32;
            u16* dW = &Ws[r][q * 32];
            #pragma unroll
            for (int x = 0; x < 32; x += 8)
                *(bf16x8*)&dW[x] = *(const bf16x8*)(wp + x);
        }
        __syncthreads();
        floatx4 acc2[2][2];
        #pragma unroll
        for (int i = 0; i < 2; i++)
            #pragma unroll
            for (int j = 0; j < 2; j++) acc2[i][j] = (floatx4)0.f;
        #pragma unroll
        for (int kk = 0; kk < KB; kk += 32) {
            bf16x8 a0 = *(const bf16x8*)&T[wm + lr     ][kk + quad * 8];
            bf16x8 a1 = *(const bf16x8*)&T[wm + 16 + lr][kk + quad * 8];
            bf16x8 b0 = *(const bf16x8*)&Ws[wn + lr     ][kk + quad * 8];
            bf16x8 b1 = *(const bf16x8*)&Ws[wn + 16 + lr][kk + quad * 8];
            acc2[0][0] = __builtin_amdgcn_mfma_f32_16x16x32_bf16(a0, b0, acc2[0][0], 0, 0, 0);
            acc2[0][1] = __builtin_amdgcn_mfma_f32_16x16x32_bf16(a0, b1, acc2[0][1], 0, 0, 0);
            acc2[1][0] = __builtin_amdgcn_mfma_f32_16x16x32_bf16(a1, b0, acc2[1][0], 0, 0, 0);
            acc2[1][1] = __builtin_amdgcn_mfma_f32_16x16x32_bf16(a1, b1, acc2[1][1], 0, 0, 0);
        }
        #pragma unroll
        for (int i = 0; i < 2; i++) {
            #pragma unroll
            for (int j = 0; j < 2; j++) {
                int gn = c0 + wn + j * 16 + lr;
                float bb = b2[gn];
                #pragma unroll
                for (int rr = 0; rr < 4; rr++) {
                    int gm = bm + wm + i * 16 + quad * 4 + rr;
                    if (gm < M) {
                        u16 val = f2b(acc2[i][j][rr] + bb);
                        if (PACK) {
                            int off = (gn < 256) ? ((gn & 127) * 2 + (gn >> 7))
                                                 : (256 + (gn & 127));
                            Ob[(size_t)gm * F3 + off] = val;
                        } else {
                            Ob[(size_t)gm * F3 + gn] = val;
                        }
                    }
                }
            }
        }
        __syncthreads();
    }
}

// Dual GEMM: U = A@Wu^T, V = A@Wv^T (K=128, Nc=128). bf16 outs.
__global__ __launch_bounds__(256) void gemm_uv(const u16* __restrict__ A,
    const u16* __restrict__ Wu, const u16* __restrict__ Wv,
    u16* __restrict__ U, u16* __restrict__ V, int M)
{
    __shared__ u16 As[64][KB + LPAD];
    __shared__ u16 Bu[64][KB + LPAD];
    __shared__ u16 Bv[64][KB + LPAD];
    const int bm = blockIdx.x * 64;
    const int bn = blockIdx.y * 64;
    const int tid = threadIdx.x;
    const int r = tid >> 2;
    const int q = tid & 3;
    const int wave = tid >> 6;
    const int lane = tid & 63;
    const int wm = (wave >> 1) * 32;
    const int wn = (wave & 1) * 32;
    const int quad = lane >> 4;
    const int lr = lane & 15;

    floatx4 au[2][2], av[2][2];
    #pragma unroll
    for (int i = 0; i < 2; i++)
        #pragma unroll
        for (int j = 0; j < 2; j++) { au[i][j] = (floatx4)0.f; av[i][j] = (floatx4)0.f; }

    {
        int gm = bm + r;
        u16* dA = &As[r][q * 32];
        if (gm < M) {
            const u16* ap = A + (size_t)gm * KB + q * 32;
            #pragma unroll
            for (int x = 0; x < 32; x += 8)
                *(bf16x8*)&dA[x] = *(const bf16x8*)(ap + x);
        } else {
            #pragma unroll
            for (int x = 0; x < 32; x += 8)
                *(bf16x8*)&dA[x] = (bf16x8)0;
        }
        int gn = bn + r;
        const u16* up = Wu + (size_t)gn * KB + q * 32;
        const u16* vp = Wv + (size_t)gn * KB + q * 32;
        u16* dU = &Bu[r][q * 32];
        u16* dV = &Bv[r][q * 32];
        #pragma unroll
        for (int x = 0; x < 32; x += 8) {
            *(bf16x8*)&dU[x] = *(const bf16x8*)(up + x);
            *(bf16x8*)&dV[x] = *(const bf16x8*)(vp + x);
        }
    }
    __syncthreads();
    #pragma unroll
    for (int kk = 0; kk < KB; kk += 32) {
        bf16x8 a0 = *(const bf16x8*)&As[wm + lr     ][kk + quad * 8];
        bf16x8 a1 = *(const bf16x8*)&As[wm + 16 + lr][kk + quad * 8];
        bf16x8 u0 = *(const bf16x8*)&Bu[wn + lr     ][kk + quad * 8];
        bf16x8 u1 = *(const bf16x8*)&Bu[wn + 16 + lr][kk + quad * 8];
        bf16x8 v0 = *(const bf16x8*)&Bv[wn + lr     ][kk + quad * 8];
        bf16x8 v1 = *(const bf16x8*)&Bv[wn + 16 + lr][kk + quad * 8];
        au[0][0] = __builtin_amdgcn_mfma_f32_16x16x32_bf16(a0, u0, au[0][0], 0, 0, 0);
        au[0][1] = __builtin_amdgcn_mfma_f32_16x16x32_bf16(a0, u1, au[0][1], 0, 0, 0);
        au[1][0] = __builtin_amdgcn_mfma_f32_16x16x32_bf16(a1, u0, au[1][0], 0, 0, 0);
        au[1][1] = __builtin_amdgcn_mfma_f32_16x16x32_bf16(a1, u1, au[1][1], 0, 0, 0);
        av[0][0] = __builtin_amdgcn_mfma_f32_16x16x32_bf16(a0, v0, av[0][0], 0, 0, 0);
        av[0][1] = __builtin_amdgcn_mfma_f32_16x16x32_bf16(a0, v1, av[0][1], 0, 0, 0);
        av[1][0] = __builtin_amdgcn_mfma_f32_16x16x32_bf16(a1, v0, av[1][0], 0, 0, 0);
        av[1][1] = __builtin_amdgcn_mfma_f32_16x16x32_bf16(a1, v1, av[1][1], 0, 0, 0);
    }
    #pragma unroll
    for (int i = 0; i < 2; i++) {
        #pragma unroll
        for (int j = 0; j < 2; j++) {
            int gn = bn + wn + j * 16 + lr;
            #pragma unroll
            for (int rr = 0; rr < 4; rr++) {
                int gm = bm + wm + i * 16 + quad * 4 + rr;
                if (gm < M) {
                    U[(size_t)gm * FD + gn] = f2b(au[i][j][rr]);
                    V[(size_t)gm * FD + gn] = f2b(av[i][j][rr]);
                }
            }
        }
    }
}

// ---------------------------------------------------------------- edge aggregate (MFMA dist_rep)
// 256 threads/node. Per 16-edge tile: dist_rep via 24 MFMAs -> planar bf16 sdrep in LDS;
// gathers via packed (pair + planar) bf16 rows: 4 VMEM ops/edge/thread, zero pad waste.
__global__ __launch_bounds__(256) void edge_mfma_kernel(
    const u16* __restrict__ rbf_bf, const float* __restrict__ cut_p,
    const float* __restrict__ sense_p, const int* __restrict__ dst_p,
    const u16* __restrict__ ewb, const float* __restrict__ eb,
    const u16* __restrict__ a_pk, const float* __restrict__ s_in,
    const float* __restrict__ v_in, const u16* __restrict__ v_pk,
    const int* __restrict__ row_ptr,
    float* __restrict__ s_out, u16* __restrict__ s_obf,
    float* __restrict__ v_out, u16* __restrict__ v_obf)
{
    __shared__ u16   sdrep[16 * SDS];   // planar bf16: [e][col] — 12.5 KB
    __shared__ float scut[16];
    __shared__ float ssen[16][4];
    __shared__ int   sdst[16];
    __shared__ float red[4 * 128];

    const int n = blockIdx.x;
    const int tid = threadIdx.x;
    const int wave = tid >> 6;
    const int lane = tid & 63;
    const int quad = lane >> 4;
    const int lr = lane & 15;
    const int f = tid & 127;
    const int half = tid >> 7;

    int beg = row_ptr[n], end = row_ptr[n + 1];
    float accs = 0.f, accv0 = 0.f, accv1 = 0.f, accv2 = 0.f;

    for (int t0 = beg; t0 < end; t0 += 16) {
        int cnt = end - t0; if (cnt > 16) cnt = 16;
        __syncthreads();   // previous tile fully consumed
        if (tid < 16) {
            scut[tid] = (tid < cnt) ? cut_p[t0 + tid] : 0.f;
            sdst[tid] = (tid < cnt) ? dst_p[t0 + tid] : 0;
        }
        if (tid >= 64 && tid < 64 + 3 * cnt) {
            int x = tid - 64;
            ssen[x / 3][x % 3] = sense_p[3 * t0 + x];
        }
        // MFMA: A = rbf rows (lane m=lr = edge), B = ew rows (6 col-tiles/wave)
        bf16x8 afrag;
        int ge = t0 + lr;
        if (ge < end) afrag = *(const bf16x8*)&rbf_bf[(size_t)ge * 32 + quad * 8];
        else          afrag = (bf16x8)0;
        floatx4 dacc[6];
        #pragma unroll
        for (int nt = 0; nt < 6; nt++) {
            int nrow = (wave * 6 + nt) * 16 + lr;
            bf16x8 bfrag = *(const bf16x8*)&ewb[(size_t)nrow * 32 + quad * 8];
            dacc[nt] = __builtin_amdgcn_mfma_f32_16x16x32_bf16(afrag, bfrag, (floatx4)0.f, 0, 0, 0);
        }
        __syncthreads();   // staged scalars visible
        // epilogue: (d + eb) * cut -> planar bf16 sdrep; C/D layout col=lr, row(edge)=quad*4+rr
        #pragma unroll
        for (int nt = 0; nt < 6; nt++) {
            int ncol = (wave * 6 + nt) * 16 + lr;
            float ebn = eb[ncol];
            #pragma unroll
            for (int rr = 0; rr < 4; rr++) {
                int e = quad * 4 + rr;
                sdrep[e * SDS + ncol] = f2b((dacc[nt][rr] + ebn) * scut[e]);
            }
        }
        __syncthreads();   // sdrep ready
        // aggregation: half h handles up to 8 edges
        int nh = cnt - half * 8; if (nh > 8) nh = 8;
        for (int k = 0; k < nh; k++) {
            int e = half * 8 + k;
            int dst = sdst[e];
            const u16* sr = &sdrep[e * SDS];
            float drv = b2f(sr[f]);
            float drs = b2f(sr[FD + f]);
            float drd = b2f(sr[2 * FD + f]);
            const u16* ar = a_pk + (size_t)dst * F3;
            u32 ap = *(const u32*)(ar + f * 2);
            float rv = b2f((u16)(ap & 0xffff)) * drv;
            float rs = b2f((u16)(ap >> 16))    * drs;
            float rd = b2f(ar[256 + f])        * drd;
            accs += rs;
            const u16* vr = v_pk + (size_t)dst * F3;
            u32 vp = *(const u32*)(vr + f * 2);
            accv0 += b2f((u16)(vp & 0xffff)) * rv + ssen[e][0] * rd;
            accv1 += b2f((u16)(vp >> 16))    * rv + ssen[e][1] * rd;
            accv2 += b2f(vr[256 + f])        * rv + ssen[e][2] * rd;
        }
    }
    // combine halves, write
    __syncthreads();
    if (half == 1) {
        red[f] = accs; red[128 + f] = accv0; red[256 + f] = accv1; red[384 + f] = accv2;
    }
    __syncthreads();
    if (half == 0) {
        accs  += red[f];       accv0 += red[128 + f];
        accv1 += red[256 + f]; accv2 += red[384 + f];
        int nb = n * FD + f;
        float so = s_in[nb] + 2.f * accs;
        s_out[nb] = so; s_obf[nb] = f2b(so);
        int vb = n * F3 + f;
        float w0 = v_in[vb]           + 2.f * accv0;
        float w1 = v_in[vb + FD]      + 2.f * accv1;
        float w2 = v_in[vb + 2 * FD]  + 2.f * accv2;
        v_out[vb]          = w0; v_obf[vb]          = f2b(w0);
        v_out[vb + FD]     = w1; v_obf[vb + FD]     = f2b(w1);
        v_out[vb + 2 * FD] = w2; v_obf[vb + 2 * FD] = f2b(w2);
    }
}

// ---------------------------------------------------------------- h build (bf16): [s, |Vv|]
__global__ __launch_bounds__(256) void build_h_kernel(const u16* __restrict__ sbf,
    const u16* __restrict__ Vv, u16* __restrict__ h)
{
    int idx = blockIdx.x * 256 + threadIdx.x;
    if (idx >= NN * FD) return;
    int n = idx >> 7, f = idx & 127;
    h[n * F2 + f] = sbf[idx];
    float x0 = b2f(Vv[n * F3 + f]);
    float x1 = b2f(Vv[n * F3 + FD + f]);
    float x2 = b2f(Vv[n * F3 + 2 * FD + f]);
    h[n * F2 + FD + f] = f2b(sqrtf(x0 * x0 + x1 * x1 + x2 * x2));
}

// ---------------------------------------------------------------- node update
__global__ __launch_bounds__(256) void update_kernel(const float* __restrict__ s_mid,
    const float* __restrict__ v_mid, const u16* __restrict__ a2,
    const u16* __restrict__ Uv, const u16* __restrict__ Vv,
    float* __restrict__ s_out, u16* __restrict__ s_obf,
    float* __restrict__ v_out, u16* __restrict__ v_pk)
{
    int idx = blockIdx.x * 256 + threadIdx.x;
    if (idx >= NN * FD) return;
    int n = idx >> 7, f = idx & 127;
    int vb = n * F3 + f;
    float u0 = b2f(Uv[vb]), u1 = b2f(Uv[vb + FD]), u2 = b2f(Uv[vb + 2 * FD]);
    float w0 = b2f(Vv[vb]), w1 = b2f(Vv[vb + FD]), w2 = b2f(Vv[vb + 2 * FD]);
    float dot = u0 * w0 + u1 * w1 + u2 * w2;
    float avv = b2f(a2[n * F3 + f]);
    float asv = b2f(a2[n * F3 + FD + f]);
    float ass = b2f(a2[n * F3 + 2 * FD + f]);
    float so = s_mid[idx] + ass + asv * dot;
    s_out[idx] = so; s_obf[idx] = f2b(so);
    float y0 = v_mid[vb]          + avv * u0;
    float y1 = v_mid[vb + FD]     + avv * u1;
    float y2 = v_mid[vb + 2 * FD] + avv * u2;
    v_out[vb]          = y0;
    v_out[vb + FD]     = y1;
    v_out[vb + 2 * FD] = y2;
    u16* vp = v_pk + (size_t)n * F3;
    *(u32*)(vp + f * 2) = (u32)f2b(y0) | ((u32)f2b(y1) << 16);
    vp[256 + f] = f2b(y2);
}

// ---------------------------------------------------------------- final head reduce (no atomics)
__global__ __launch_bounds__(256) void node_out_kernel(const float* __restrict__ t,
    const float* __restrict__ ow2, const float* __restrict__ ob2,
    float* __restrict__ nodeval)
{
    int gt = blockIdx.x * 256 + threadIdx.x;
    int n = gt >> 6;
    int lane = threadIdx.x & 63;
    if (n >= NN) return;
    float v = t[n * FD + lane] * ow2[lane] + t[n * FD + 64 + lane] * ow2[64 + lane];
    #pragma unroll
    for (int off = 32; off > 0; off >>= 1) v += __shfl_down(v, off);
    if (lane == 0) nodeval[n] = v + ob2[0];
}

__global__ __launch_bounds__(1024) void mol_reduce_kernel(const float* __restrict__ nodeval,
    const int* __restrict__ gidx, float* __restrict__ out)
{
    __shared__ float mol[NMOL];
    int tid = threadIdx.x;
    if (tid < NMOL) mol[tid] = 0.f;
    __syncthreads();
    int cur = -1; float acc = 0.f;
    for (int x = tid; x < NN; x += 1024) {
        int g = gidx[x];
        float v = nodeval[x];
        if (g != cur) {
            if (cur >= 0) atomicAdd(&mol[cur], acc);
            cur = g; acc = v;
        } else acc += v;
    }
    if (cur >= 0) atomicAdd(&mol[cur], acc);
    __syncthreads();
    if (tid < NMOL) out[tid] = mol[tid];
}

// ---------------------------------------------------------------- launch
extern "C" void kernel_launch(void* const* d_in, const int* in_sizes, int n_in,
                              void* d_out, int out_size, void* d_ws, size_t ws_size,
                              hipStream_t stream)
{
    const int*   z     = (const int*)d_in[0];
    const int*   graph = (const int*)d_in[1];
    const float* dist  = (const float*)d_in[2];
    const float* sense = (const float*)d_in[3];
    const int*   gidx  = (const int*)d_in[4];
    const float* emb   = (const float*)d_in[5];
    const float* mw1   = (const float*)d_in[6];
    const float* mb1   = (const float*)d_in[7];
    const float* mw2   = (const float*)d_in[8];
    const float* mb2   = (const float*)d_in[9];
    const float* ew    = (const float*)d_in[10];
    const float* eb    = (const float*)d_in[11];
    const float* uw    = (const float*)d_in[12];
    const float* vw    = (const float*)d_in[13];
    const float* aw1   = (const float*)d_in[14];
    const float* ab1   = (const float*)d_in[15];
    const float* aw2   = (const float*)d_in[16];
    const float* ab2   = (const float*)d_in[17];
    const float* ow1   = (const float*)d_in[18];
    const float* ob1   = (const float*)d_in[19];
    const float* ow2   = (const float*)d_in[20];
    const float* ob2   = (const float*)d_in[21];
    float* out = (float*)d_out;

    // ---- workspace carve-up ----
    float* W = (float*)d_ws;
    float* s_a    = W; W += (size_t)NN * FD;
    float* s_b    = W; W += (size_t)NN * FD;     // aliased as tfin after last iter
    float* v_a    = W; W += (size_t)NN * F3;
    float* v_b    = W; W += (size_t)NN * F3;
    float* cut_p  = W; W += (size_t)NE;
    float* sns_p  = W; W += (size_t)NE * 3;
    float* nodeval= W; W += (size_t)NN;
    u16* U = (u16*)W;
    u16* sbf_a = U; U += (size_t)NN * FD;
    u16* sbf_b = U; U += (size_t)NN * FD;
    u16* vbf_b = U; U += (size_t)NN * F3;
    u16* a_pk  = U; U += (size_t)NN * F3;
    u16* v_pk  = U; U += (size_t)NN * F3;
    u16* h_bf  = U; U += (size_t)NN * F2;
    u16* a2_bf = U; U += (size_t)NN * F3;
    u16* Uv_bf = U; U += (size_t)NN * F3;
    u16* Vv_bf = U; U += (size_t)NN * F3;
    u16* rbf_bf= U; U += (size_t)NE * 32;
    u16* ewb   = U; U += (size_t)NITER * F3 * 32;
    u16* wb    = U; U += 557056;
    int* ip = (int*)U;
    int* row_ptr   = ip; ip += NN + 1;
    int* cnt       = ip; ip += NN;
    int* cursor    = ip; ip += NN;
    int* edge_list = ip; ip += NE;
    int* dst_p     = ip; ip += NE;
    float* tfin = s_b;

    // bf16 weight table offsets
    u16* wb_mw1 = wb;            // 3*128*128
    u16* wb_mw2 = wb + 49152;    // 3*384*128
    u16* wb_uw  = wb + 196608;   // 3*128*128
    u16* wb_vw  = wb + 245760;   // 3*128*128
    u16* wb_aw1 = wb + 294912;   // 3*128*256
    u16* wb_aw2 = wb + 393216;   // 3*384*128
    u16* wb_ow1 = wb + 540672;   // 128*128
    const int WTOT = 557056;

    const int TB = 256;
    dim3 b256(TB);

    // --- precompute ---
    cvt_w_kernel<<<dim3((WTOT + TB - 1) / TB), b256, 0, stream>>>(
        mw1, 49152, mw2, 147456, uw, 49152, vw, 49152, aw1, 98304, aw2, 147456,
        ow1, 16384, wb);
    cvt_ew_kernel<<<dim3((NITER * F3 * 32 + TB - 1) / TB), b256, 0, stream>>>(ew, ewb);
    embed_kernel<<<dim3((NN * FD + TB - 1) / TB), b256, 0, stream>>>(z, emb, s_a, sbf_a);
    zero_f_kernel<<<dim3((NN * F3 + TB - 1) / TB), b256, 0, stream>>>(v_a, NN * F3);
    zero_i_kernel<<<dim3((NN * F3 / 2 + TB - 1) / TB), b256, 0, stream>>>((int*)v_pk, NN * F3 / 2);
    zero_i_kernel<<<dim3((NN + TB - 1) / TB), b256, 0, stream>>>(cnt, NN);
    csr_count_kernel<<<dim3((NE + TB - 1) / TB), b256, 0, stream>>>(graph, cnt);
    csr_scan_kernel<<<dim3(1), dim3(1024), 0, stream>>>(cnt, row_ptr, cursor);
    csr_scatter_kernel<<<dim3((NE + TB - 1) / TB), b256, 0, stream>>>(graph, cursor, edge_list);
    edge_stream_kernel<<<dim3((NE + TB - 1) / TB), b256, 0, stream>>>(
        edge_list, graph, dist, sense, rbf_bf, cut_p, sns_p, dst_p);

    dim3 gM((NN + 63) / 64);                   // fused MLPs
    dim3 gN2((NN + 63) / 64, FD / 64);         // final head
    dim3 gV2((3 * NN + 63) / 64, FD / 64);     // M=3N, Nc=128

    for (int i = 0; i < NITER; i++) {
        mlp_kernel<128, true><<<gM, b256, 0, stream>>>(sbf_a,
            wb_mw1 + (size_t)i * FD * FD, mb1 + (size_t)i * FD,
            wb_mw2 + (size_t)i * F3 * FD, mb2 + (size_t)i * F3, a_pk, NN);
        edge_mfma_kernel<<<dim3(NN), b256, 0, stream>>>(
            rbf_bf, cut_p, sns_p, dst_p,
            ewb + (size_t)i * F3 * 32, eb + (size_t)i * F3,
            a_pk, s_a, v_a, v_pk, row_ptr, s_b, sbf_b, v_b, vbf_b);
        gemm_uv<<<gV2, b256, 0, stream>>>(vbf_b, wb_uw + (size_t)i * FD * FD,
            wb_vw + (size_t)i * FD * FD, Uv_bf, Vv_bf, 3 * NN);
        build_h_kernel<<<dim3((NN * FD + TB - 1) / TB), b256, 0, stream>>>(sbf_b, Vv_bf, h_bf);
        mlp_kernel<256, false><<<gM, b256, 0, stream>>>(h_bf,
            wb_aw1 + (size_t)i * FD * F2, ab1 + (size_t)i * FD,
            wb_aw2 + (size_t)i * F3 * FD, ab2 + (size_t)i * F3, a2_bf, NN);
        update_kernel<<<dim3((NN * FD + TB - 1) / TB), b256, 0, stream>>>(
            s_b, v_b, a2_bf, Uv_bf, Vv_bf, s_a, sbf_a, v_a, v_pk);
    }

    gemm_bf16<true><<<gN2, b256, 0, stream>>>(sbf_a, wb_ow1, ob1, tfin, NN, FD, FD);
    node_out_kernel<<<dim3((NN * 64 + TB - 1) / TB), b256, 0, stream>>>(tfin, ow2, ob2, nodeval);
    mol_reduce_kernel<<<dim3(1), dim3(1024), 0, stream>>>(nodeval, gidx, out);
}